// Round 1
// baseline (329.459 us; speedup 1.0000x reference)
//
#include <hip/hip_runtime.h>
#include <hip/hip_bf16.h>

// Problem: SimpleAugmentedCNN forward, B=16, H=W=32, NH=4, DKH=DVH=10.
// Pipeline: conv1(3->64,3x3) -> BN(train stats)+relu -> {qkv 1x1 (64->120),
// rectangle-sum stats for pooled convo} -> attention w/ relative logits ->
// pooled attn -> (convo-pool matvec, attno 1x1, fc) fused final kernel.
// conv_out is never materialized: mean-pool commutes with conv taps.

#define WS_H       0
#define WS_QKV     1048576          // 16*64*1024
#define WS_ATTN    (WS_QKV + 1966080)   // 16*120*1024
#define WS_SCALE   (WS_ATTN + 655360)   // 16*4*1024*10
#define WS_SHIFT   (WS_SCALE + 64)
#define WS_SSTAT   (WS_SHIFT + 64)
#define WS_POOLA   (WS_SSTAT + 9216)    // 16*64*9

// ---------------- conv1: 3->64, 3x3 SAME ----------------
__global__ __launch_bounds__(256) void conv1_kernel(
    const float* __restrict__ x, const float* __restrict__ w,
    const float* __restrict__ bias, float* __restrict__ h) {
  int b = blockIdx.x >> 6, co = blockIdx.x & 63;
  int t = threadIdx.x;
  float wreg[27];
#pragma unroll
  for (int i = 0; i < 27; ++i) wreg[i] = w[co * 27 + i];
  float bv = bias[co];
  for (int j = 0; j < 4; ++j) {
    int s = j * 256 + t;
    int yy = s >> 5, xx = s & 31;
    float acc = bv;
#pragma unroll
    for (int ci = 0; ci < 3; ++ci) {
#pragma unroll
      for (int dy = 0; dy < 3; ++dy) {
        int sy = yy + dy - 1;
        if (sy < 0 || sy > 31) continue;
#pragma unroll
        for (int dx = 0; dx < 3; ++dx) {
          int sx = xx + dx - 1;
          if (sx < 0 || sx > 31) continue;
          acc += wreg[ci * 9 + dy * 3 + dx] * x[((b * 3 + ci) * 32 + sy) * 32 + sx];
        }
      }
    }
    h[((b * 64 + co) * 32 + yy) * 32 + xx] = acc;
  }
}

// ---------------- BN stats: per-channel mean/var over (B,H,W) ----------------
__global__ __launch_bounds__(256) void bn_stats_kernel(
    const float* __restrict__ h, const float* __restrict__ g,
    const float* __restrict__ beta, float* __restrict__ scale,
    float* __restrict__ shift) {
  int c = blockIdx.x;
  int t = threadIdx.x;
  float s = 0.f, s2 = 0.f;
  for (int b = 0; b < 16; ++b) {
    const float* p = h + (b * 64 + c) * 1024;
    for (int j = t; j < 1024; j += 256) {
      float v = p[j];
      s += v;
      s2 += v * v;
    }
  }
  __shared__ float r1[256], r2[256];
  r1[t] = s; r2[t] = s2;
  __syncthreads();
  for (int off = 128; off > 0; off >>= 1) {
    if (t < off) { r1[t] += r1[t + off]; r2[t] += r2[t + off]; }
    __syncthreads();
  }
  if (t == 0) {
    float mu = r1[0] * (1.f / 16384.f);
    float var = r2[0] * (1.f / 16384.f) - mu * mu;
    float sc = g[c] * rsqrtf(var + 1e-5f);
    scale[c] = sc;
    shift[c] = beta[c] - mu * sc;
  }
}

// ---------------- BN apply + relu (in place, float4) ----------------
__global__ __launch_bounds__(256) void bn_apply_kernel(
    float* __restrict__ h, const float* __restrict__ scale,
    const float* __restrict__ shift) {
  int idx = blockIdx.x * 256 + threadIdx.x;   // float4 index, 262144 total
  int c = (idx >> 8) & 63;
  float sc = scale[c], sh = shift[c];
  float4* p = reinterpret_cast<float4*>(h) + idx;
  float4 v = *p;
  v.x = fmaxf(0.f, v.x * sc + sh);
  v.y = fmaxf(0.f, v.y * sc + sh);
  v.z = fmaxf(0.f, v.z * sc + sh);
  v.w = fmaxf(0.f, v.w * sc + sh);
  *p = v;
}

// ---------------- rectangle sums S[b,ci,dy,dx] for pooled convo ----------------
__global__ __launch_bounds__(256) void sstat_kernel(
    const float* __restrict__ h, float* __restrict__ Sstat) {
  int bc = blockIdx.x;   // b*64+ci
  const float* p = h + bc * 1024;
  int t = threadIdx.x;
  float tot = 0, r0 = 0, r31 = 0, c0 = 0, c31 = 0;
  for (int j = t; j < 1024; j += 256) {
    float v = p[j];
    tot += v;
    if (j < 32) r0 += v;
    if (j >= 992) r31 += v;
    if ((j & 31) == 0) c0 += v;
    if ((j & 31) == 31) c31 += v;
  }
  __shared__ float red[5][256];
  red[0][t] = tot; red[1][t] = r0; red[2][t] = r31; red[3][t] = c0; red[4][t] = c31;
  __syncthreads();
  for (int off = 128; off > 0; off >>= 1) {
    if (t < off)
      for (int k = 0; k < 5; ++k) red[k][t] += red[k][t + off];
    __syncthreads();
  }
  if (t == 0) {
    float T = red[0][0], R0 = red[1][0], R31 = red[2][0], C0 = red[3][0], C31 = red[4][0];
    float h00 = p[0], h0c = p[31], hr0 = p[992], hrc = p[1023];
    // dy=0 excludes row31; dy=2 excludes row0; dx likewise for cols.
    float xr[3] = {R31, 0.f, R0};
    float xc[3] = {C31, 0.f, C0};
    float corner[3][3] = {{hrc, 0.f, hr0}, {0.f, 0.f, 0.f}, {h0c, 0.f, h00}};
    for (int dy = 0; dy < 3; ++dy)
      for (int dx = 0; dx < 3; ++dx)
        Sstat[bc * 9 + dy * 3 + dx] = T - xr[dy] - xc[dx] + corner[dy][dx];
  }
}

// ---------------- qkv 1x1 conv: 64 -> 120 ----------------
__global__ __launch_bounds__(256) void qkv_kernel(
    const float* __restrict__ h, const float* __restrict__ w,
    const float* __restrict__ bias, float* __restrict__ qkv) {
  int bid = blockIdx.x;               // (b*120+co)*4 + sq
  int sq = bid & 3;
  int rest = bid >> 2;
  int co = rest % 120;
  int b = rest / 120;
  int s = sq * 256 + threadIdx.x;
  const float* hp = h + b * 65536 + s;
  const float* wp = w + co * 64;      // uniform across block -> scalar loads
  float acc = bias[co];
#pragma unroll
  for (int ci = 0; ci < 64; ++ci) acc += wp[ci] * hp[ci * 1024];
  qkv[(b * 120 + co) * 1024 + s] = acc;
}

// ---------------- attention: 1 thread per query, flash-style ----------------
// grid 256 = b*16 + hd*4 + qt; block 256 threads (256 queries).
// K,V staged in LDS in [key][12]-padded rows, two 512-key halves.
__global__ __launch_bounds__(256) void attn_kernel(
    const float* __restrict__ qkv, const float* __restrict__ relw,
    const float* __restrict__ relh, float* __restrict__ attn_pre) {
  int bid = blockIdx.x;
  int qt = bid & 3, hd = (bid >> 2) & 3, b = bid >> 4;
  int t = threadIdx.x;

  __shared__ float Ks[512][12];
  __shared__ float Vs[512][12];
  __shared__ float Rw[63][10];
  __shared__ float Rh[63][10];

  for (int i = t; i < 630; i += 256) {
    Rw[i / 10][i % 10] = relw[i];
    Rh[i / 10][i % 10] = relh[i];
  }

  int n = qt * 256 + t;
  int x = n >> 5, y = n & 31;
  const float* qbase = qkv + ((size_t)b * 120 + hd * 10) * 1024 + n;
  float q[10];
#pragma unroll
  for (int d = 0; d < 10; ++d) q[d] = qbase[d * 1024] * 0.31622776601683794f;

  __syncthreads();   // Rw/Rh ready

  float rw[32], rh[32];
#pragma unroll
  for (int j = 0; j < 32; ++j) {
    int dw = 31 + j - y;
    int dh = 31 + j - x;
    float sw = 0.f, sh = 0.f;
#pragma unroll
    for (int d = 0; d < 10; ++d) {
      sw += q[d] * Rw[dw][d];
      sh += q[d] * Rh[dh][d];
    }
    rw[j] = sw;
    rh[j] = sh;
  }

  float m_run = -1e30f, l_run = 0.f;
  float acc[10];
#pragma unroll
  for (int d = 0; d < 10; ++d) acc[d] = 0.f;

  const float* kbase = qkv + ((size_t)b * 120 + 40 + hd * 10) * 1024;
  const float* vbase = qkv + ((size_t)b * 120 + 80 + hd * 10) * 1024;

  for (int half = 0; half < 2; ++half) {
    __syncthreads();   // previous half's compute done before LDS overwrite
#pragma unroll
    for (int d = 0; d < 10; ++d) {
      for (int mm = t; mm < 512; mm += 256) {
        Ks[mm][d] = kbase[d * 1024 + half * 512 + mm];
        Vs[mm][d] = vbase[d * 1024 + half * 512 + mm];
      }
    }
    __syncthreads();

    for (int xp = 0; xp < 16; ++xp) {
      float rhv = rh[half * 16 + xp];
      float lx[32];
      float cmax = -1e30f;
#pragma unroll
      for (int yp = 0; yp < 32; ++yp) {
        const float* kp = &Ks[xp * 32 + yp][0];
        float4 k0 = *reinterpret_cast<const float4*>(kp);
        float4 k1 = *reinterpret_cast<const float4*>(kp + 4);
        float2 k2 = *reinterpret_cast<const float2*>(kp + 8);
        float dot = q[0] * k0.x + q[1] * k0.y + q[2] * k0.z + q[3] * k0.w
                  + q[4] * k1.x + q[5] * k1.y + q[6] * k1.z + q[7] * k1.w
                  + q[8] * k2.x + q[9] * k2.y;
        float lv = dot + rw[yp] + rhv;
        lx[yp] = lv;
        cmax = fmaxf(cmax, lv);
      }
      float newm = fmaxf(m_run, cmax);
      float alpha = __expf(m_run - newm);
      l_run *= alpha;
#pragma unroll
      for (int d = 0; d < 10; ++d) acc[d] *= alpha;
#pragma unroll
      for (int yp = 0; yp < 32; ++yp) {
        float p = __expf(lx[yp] - newm);
        l_run += p;
        const float* vp = &Vs[xp * 32 + yp][0];
        float4 v0 = *reinterpret_cast<const float4*>(vp);
        float4 v1 = *reinterpret_cast<const float4*>(vp + 4);
        float2 v2 = *reinterpret_cast<const float2*>(vp + 8);
        acc[0] += p * v0.x; acc[1] += p * v0.y; acc[2] += p * v0.z; acc[3] += p * v0.w;
        acc[4] += p * v1.x; acc[5] += p * v1.y; acc[6] += p * v1.z; acc[7] += p * v1.w;
        acc[8] += p * v2.x; acc[9] += p * v2.y;
      }
      m_run = newm;
    }
  }

  float inv = 1.f / l_run;
  float* ob = attn_pre + (((size_t)b * 4 + hd) * 1024 + n) * 10;
#pragma unroll
  for (int d = 0; d < 10; ++d) ob[d] = acc[d] * inv;
}

// ---------------- pool attn (faithful buggy-reshape view is just flat ranges) ----------------
__global__ __launch_bounds__(256) void pool_attn_kernel(
    const float* __restrict__ attn_pre, float* __restrict__ pooledA) {
  int bc = blockIdx.x;   // b*40 + c, contiguous 1024-range per channel
  const float* p = attn_pre + bc * 1024;
  int t = threadIdx.x;
  float s = 0.f;
  for (int j = t; j < 1024; j += 256) s += p[j];
  __shared__ float red[256];
  red[t] = s;
  __syncthreads();
  for (int off = 128; off > 0; off >>= 1) {
    if (t < off) red[t] += red[t + off];
    __syncthreads();
  }
  if (t == 0) pooledA[bc] = red[0] * (1.f / 1024.f);
}

// ---------------- final: pooled convo matvec + attno + fc ----------------
__global__ __launch_bounds__(128) void final_kernel(
    const float* __restrict__ Sstat, const float* __restrict__ pooledA,
    const float* __restrict__ convo_w, const float* __restrict__ convo_b,
    const float* __restrict__ attno_w, const float* __restrict__ attno_b,
    const float* __restrict__ fc_w, const float* __restrict__ fc_b,
    float* __restrict__ out) {
  int b = blockIdx.x;
  int t = threadIdx.x;
  __shared__ float Sl[576];
  __shared__ float pooled[128];
  __shared__ float pa[40];
  for (int j = t; j < 576; j += 128) Sl[j] = Sstat[b * 576 + j];
  if (t < 40) pa[t] = pooledA[b * 40 + t];
  __syncthreads();
  if (t < 88) {
    float acc = 0.f;
    for (int j = 0; j < 576; ++j) acc += convo_w[t * 576 + j] * Sl[j];
    pooled[t] = convo_b[t] + acc * (1.f / 1024.f);
  } else if (t < 128) {
    int co = t - 88;
    float acc = attno_b[co];
    for (int ci = 0; ci < 40; ++ci) acc += attno_w[co * 40 + ci] * pa[ci];
    pooled[88 + co] = acc;
  }
  __syncthreads();
  if (t < 100) {
    float acc = fc_b[t];
    for (int c = 0; c < 128; ++c) acc += fc_w[t * 128 + c] * pooled[c];
    out[b * 100 + t] = acc;
  }
}

extern "C" void kernel_launch(void* const* d_in, const int* in_sizes, int n_in,
                              void* d_out, int out_size, void* d_ws, size_t ws_size,
                              hipStream_t stream) {
  const float* x        = (const float*)d_in[0];
  const float* conv1_w  = (const float*)d_in[1];
  const float* conv1_b  = (const float*)d_in[2];
  const float* bn1_g    = (const float*)d_in[3];
  const float* bn1_b    = (const float*)d_in[4];
  const float* convo_w  = (const float*)d_in[5];
  const float* convo_b  = (const float*)d_in[6];
  const float* qkv_w    = (const float*)d_in[7];
  const float* qkv_b    = (const float*)d_in[8];
  const float* attno_w  = (const float*)d_in[9];
  const float* attno_b  = (const float*)d_in[10];
  const float* key_rel_h = (const float*)d_in[11];
  const float* key_rel_w = (const float*)d_in[12];
  const float* fc_w     = (const float*)d_in[13];
  const float* fc_b     = (const float*)d_in[14];

  float* ws       = (float*)d_ws;
  float* h        = ws + WS_H;
  float* qkvb     = ws + WS_QKV;
  float* attn_pre = ws + WS_ATTN;
  float* scale    = ws + WS_SCALE;
  float* shift    = ws + WS_SHIFT;
  float* Sstat    = ws + WS_SSTAT;
  float* pooledA  = ws + WS_POOLA;

  conv1_kernel<<<1024, 256, 0, stream>>>(x, conv1_w, conv1_b, h);
  bn_stats_kernel<<<64, 256, 0, stream>>>(h, bn1_g, bn1_b, scale, shift);
  bn_apply_kernel<<<1024, 256, 0, stream>>>(h, scale, shift);
  sstat_kernel<<<1024, 256, 0, stream>>>(h, Sstat);
  qkv_kernel<<<7680, 256, 0, stream>>>(h, qkv_w, qkv_b, qkvb);
  attn_kernel<<<256, 256, 0, stream>>>(qkvb, key_rel_w, key_rel_h, attn_pre);
  pool_attn_kernel<<<640, 256, 0, stream>>>(attn_pre, pooledA);
  final_kernel<<<16, 128, 0, stream>>>(Sstat, pooledA, convo_w, convo_b,
                                       attno_w, attno_b, fc_w, fc_b, (float*)d_out);
}

// Round 2
// 289.553 us; speedup vs baseline: 1.1378x; 1.1378x over previous
//
#include <hip/hip_runtime.h>
#include <hip/hip_bf16.h>

// Problem: SimpleAugmentedCNN forward, B=16, H=W=32, NH=4, DKH=DVH=10.
// conv1(3->64,3x3) -> BN(train)+relu -> {qkv 1x1, rect-sum stats} ->
// split-K flash attention (4 key splits, partial m/l/acc + combine) ->
// pooled attn -> (convo-pool matvec, attno, fc) final kernel.
// conv_out never materialized: mean-pool commutes with the conv taps.

#define WS_H       0
#define WS_QKV     1048576              // 16*64*1024
#define WS_ATTN    (WS_QKV + 1966080)   // 16*120*1024
#define WS_SCALE   (WS_ATTN + 655360)   // 16*4*1024*10
#define WS_SHIFT   (WS_SCALE + 64)
#define WS_SSTAT   (WS_SHIFT + 64)
#define WS_POOLA   (WS_SSTAT + 9216)
#define WS_PART    (WS_POOLA + 640)     // 65536 queries * 4 splits * 12 floats

#define NSPLIT 4

// ---------------- conv1: 3->64, 3x3 SAME ----------------
__global__ __launch_bounds__(256) void conv1_kernel(
    const float* __restrict__ x, const float* __restrict__ w,
    const float* __restrict__ bias, float* __restrict__ h) {
  int b = blockIdx.x >> 6, co = blockIdx.x & 63;
  int t = threadIdx.x;
  float wreg[27];
#pragma unroll
  for (int i = 0; i < 27; ++i) wreg[i] = w[co * 27 + i];
  float bv = bias[co];
  for (int j = 0; j < 4; ++j) {
    int s = j * 256 + t;
    int yy = s >> 5, xx = s & 31;
    float acc = bv;
#pragma unroll
    for (int ci = 0; ci < 3; ++ci) {
#pragma unroll
      for (int dy = 0; dy < 3; ++dy) {
        int sy = yy + dy - 1;
        if (sy < 0 || sy > 31) continue;
#pragma unroll
        for (int dx = 0; dx < 3; ++dx) {
          int sx = xx + dx - 1;
          if (sx < 0 || sx > 31) continue;
          acc += wreg[ci * 9 + dy * 3 + dx] * x[((b * 3 + ci) * 32 + sy) * 32 + sx];
        }
      }
    }
    h[((b * 64 + co) * 32 + yy) * 32 + xx] = acc;
  }
}

// ---------------- BN stats ----------------
__global__ __launch_bounds__(256) void bn_stats_kernel(
    const float* __restrict__ h, const float* __restrict__ g,
    const float* __restrict__ beta, float* __restrict__ scale,
    float* __restrict__ shift) {
  int c = blockIdx.x;
  int t = threadIdx.x;
  float s = 0.f, s2 = 0.f;
  for (int b = 0; b < 16; ++b) {
    const float* p = h + (b * 64 + c) * 1024;
    for (int j = t; j < 1024; j += 256) {
      float v = p[j];
      s += v;
      s2 += v * v;
    }
  }
  __shared__ float r1[256], r2[256];
  r1[t] = s; r2[t] = s2;
  __syncthreads();
  for (int off = 128; off > 0; off >>= 1) {
    if (t < off) { r1[t] += r1[t + off]; r2[t] += r2[t + off]; }
    __syncthreads();
  }
  if (t == 0) {
    float mu = r1[0] * (1.f / 16384.f);
    float var = r2[0] * (1.f / 16384.f) - mu * mu;
    float sc = g[c] * rsqrtf(var + 1e-5f);
    scale[c] = sc;
    shift[c] = beta[c] - mu * sc;
  }
}

// ---------------- BN apply + relu ----------------
__global__ __launch_bounds__(256) void bn_apply_kernel(
    float* __restrict__ h, const float* __restrict__ scale,
    const float* __restrict__ shift) {
  int idx = blockIdx.x * 256 + threadIdx.x;
  int c = (idx >> 8) & 63;
  float sc = scale[c], sh = shift[c];
  float4* p = reinterpret_cast<float4*>(h) + idx;
  float4 v = *p;
  v.x = fmaxf(0.f, v.x * sc + sh);
  v.y = fmaxf(0.f, v.y * sc + sh);
  v.z = fmaxf(0.f, v.z * sc + sh);
  v.w = fmaxf(0.f, v.w * sc + sh);
  *p = v;
}

// ---------------- rectangle sums for pooled convo ----------------
__global__ __launch_bounds__(256) void sstat_kernel(
    const float* __restrict__ h, float* __restrict__ Sstat) {
  int bc = blockIdx.x;
  const float* p = h + bc * 1024;
  int t = threadIdx.x;
  float tot = 0, r0 = 0, r31 = 0, c0 = 0, c31 = 0;
  for (int j = t; j < 1024; j += 256) {
    float v = p[j];
    tot += v;
    if (j < 32) r0 += v;
    if (j >= 992) r31 += v;
    if ((j & 31) == 0) c0 += v;
    if ((j & 31) == 31) c31 += v;
  }
  __shared__ float red[5][256];
  red[0][t] = tot; red[1][t] = r0; red[2][t] = r31; red[3][t] = c0; red[4][t] = c31;
  __syncthreads();
  for (int off = 128; off > 0; off >>= 1) {
    if (t < off)
      for (int k = 0; k < 5; ++k) red[k][t] += red[k][t + off];
    __syncthreads();
  }
  if (t == 0) {
    float T = red[0][0], R0 = red[1][0], R31 = red[2][0], C0 = red[3][0], C31 = red[4][0];
    float h00 = p[0], h0c = p[31], hr0 = p[992], hrc = p[1023];
    float xr[3] = {R31, 0.f, R0};
    float xc[3] = {C31, 0.f, C0};
    float corner[3][3] = {{hrc, 0.f, hr0}, {0.f, 0.f, 0.f}, {h0c, 0.f, h00}};
    for (int dy = 0; dy < 3; ++dy)
      for (int dx = 0; dx < 3; ++dx)
        Sstat[bc * 9 + dy * 3 + dx] = T - xr[dy] - xc[dx] + corner[dy][dx];
  }
}

// ---------------- qkv 1x1 conv: 64 -> 120 ----------------
__global__ __launch_bounds__(256) void qkv_kernel(
    const float* __restrict__ h, const float* __restrict__ w,
    const float* __restrict__ bias, float* __restrict__ qkv) {
  int bid = blockIdx.x;
  int sq = bid & 3;
  int rest = bid >> 2;
  int co = rest % 120;
  int b = rest / 120;
  int s = sq * 256 + threadIdx.x;
  const float* hp = h + b * 65536 + s;
  const float* wp = w + co * 64;
  float acc = bias[co];
#pragma unroll
  for (int ci = 0; ci < 64; ++ci) acc += wp[ci] * hp[ci * 1024];
  qkv[(b * 120 + co) * 1024 + s] = acc;
}

// ---------------- split-K flash attention ----------------
// grid 1024 = ((b*4+hd)*4+qt)*NSPLIT + ks. Block = 256 queries.
// Split ks covers keys [ks*256, ks*256+256) (x' rows ks*8 .. ks*8+7).
// Writes partial (m, l, acc[10]) per (query, split).
__global__ __launch_bounds__(256) void attn_split_kernel(
    const float* __restrict__ qkv, const float* __restrict__ relw,
    const float* __restrict__ relh, float* __restrict__ part) {
  int bid = blockIdx.x;
  int ks = bid & (NSPLIT - 1);
  int qt = (bid / NSPLIT) & 3;
  int hd = (bid / (NSPLIT * 4)) & 3;
  int b = bid / (NSPLIT * 16);
  int t = threadIdx.x;

  __shared__ float Ks[256][12];
  __shared__ float Vs[256][12];
  __shared__ float Rw[63][10];
  __shared__ float Rh[63][10];

  for (int i = t; i < 630; i += 256) {
    Rw[i / 10][i % 10] = relw[i];
    Rh[i / 10][i % 10] = relh[i];
  }

  int n = qt * 256 + t;
  int x = n >> 5, y = n & 31;
  const float* qbase = qkv + ((size_t)b * 120 + hd * 10) * 1024 + n;
  float q[10];
#pragma unroll
  for (int d = 0; d < 10; ++d) q[d] = qbase[d * 1024] * 0.31622776601683794f;

  // stage K,V: one key per thread, coalesced global reads
  const float* kbase = qkv + ((size_t)b * 120 + 40 + hd * 10) * 1024 + ks * 256;
  const float* vbase = qkv + ((size_t)b * 120 + 80 + hd * 10) * 1024 + ks * 256;
#pragma unroll
  for (int d = 0; d < 10; ++d) {
    Ks[t][d] = kbase[d * 1024 + t];
    Vs[t][d] = vbase[d * 1024 + t];
  }
  __syncthreads();

  float rw[32], rh[8];
#pragma unroll
  for (int j = 0; j < 32; ++j) {
    int dw = 31 + j - y;
    float sw = 0.f;
#pragma unroll
    for (int d = 0; d < 10; ++d) sw += q[d] * Rw[dw][d];
    rw[j] = sw;
  }
#pragma unroll
  for (int j = 0; j < 8; ++j) {
    int dh = 31 + ks * 8 + j - x;
    float sh = 0.f;
#pragma unroll
    for (int d = 0; d < 10; ++d) sh += q[d] * Rh[dh][d];
    rh[j] = sh;
  }

  float m_run = -1e30f, l_run = 0.f;
  float acc[10];
#pragma unroll
  for (int d = 0; d < 10; ++d) acc[d] = 0.f;

  for (int xpl = 0; xpl < 8; ++xpl) {
    float rhv = rh[xpl];
    float lx[32];
    float cmax = -1e30f;
#pragma unroll
    for (int yp = 0; yp < 32; ++yp) {
      const float* kp = &Ks[xpl * 32 + yp][0];
      float4 k0 = *reinterpret_cast<const float4*>(kp);
      float4 k1 = *reinterpret_cast<const float4*>(kp + 4);
      float2 k2 = *reinterpret_cast<const float2*>(kp + 8);
      float dot = q[0] * k0.x + q[1] * k0.y + q[2] * k0.z + q[3] * k0.w
                + q[4] * k1.x + q[5] * k1.y + q[6] * k1.z + q[7] * k1.w
                + q[8] * k2.x + q[9] * k2.y;
      float lv = dot + rw[yp] + rhv;
      lx[yp] = lv;
      cmax = fmaxf(cmax, lv);
    }
    float newm = fmaxf(m_run, cmax);
    float alpha = __expf(m_run - newm);
    l_run *= alpha;
#pragma unroll
    for (int d = 0; d < 10; ++d) acc[d] *= alpha;
#pragma unroll
    for (int yp = 0; yp < 32; ++yp) {
      float p = __expf(lx[yp] - newm);
      l_run += p;
      const float* vp = &Vs[xpl * 32 + yp][0];
      float4 v0 = *reinterpret_cast<const float4*>(vp);
      float4 v1 = *reinterpret_cast<const float4*>(vp + 4);
      float2 v2 = *reinterpret_cast<const float2*>(vp + 8);
      acc[0] += p * v0.x; acc[1] += p * v0.y; acc[2] += p * v0.z; acc[3] += p * v0.w;
      acc[4] += p * v1.x; acc[5] += p * v1.y; acc[6] += p * v1.z; acc[7] += p * v1.w;
      acc[8] += p * v2.x; acc[9] += p * v2.y;
    }
    m_run = newm;
  }

  // partial layout: part[qid*48 + ks*12 + j], qid = ((b*4+hd)*4+qt)*256+t
  int qid = ((b * 4 + hd) * 4 + qt) * 256 + t;
  float4* pp = reinterpret_cast<float4*>(part + (size_t)qid * 48 + ks * 12);
  pp[0] = make_float4(m_run, l_run, acc[0], acc[1]);
  pp[1] = make_float4(acc[2], acc[3], acc[4], acc[5]);
  pp[2] = make_float4(acc[6], acc[7], acc[8], acc[9]);
}

// ---------------- combine split partials ----------------
__global__ __launch_bounds__(256) void attn_combine_kernel(
    const float* __restrict__ part, float* __restrict__ attn_pre) {
  int qid = blockIdx.x * 256 + threadIdx.x;   // 65536
  const float4* pp = reinterpret_cast<const float4*>(part + (size_t)qid * 48);
  float m[NSPLIT], l[NSPLIT], a[NSPLIT][10];
#pragma unroll
  for (int s = 0; s < NSPLIT; ++s) {
    float4 u0 = pp[s * 3], u1 = pp[s * 3 + 1], u2 = pp[s * 3 + 2];
    m[s] = u0.x; l[s] = u0.y;
    a[s][0] = u0.z; a[s][1] = u0.w;
    a[s][2] = u1.x; a[s][3] = u1.y; a[s][4] = u1.z; a[s][5] = u1.w;
    a[s][6] = u2.x; a[s][7] = u2.y; a[s][8] = u2.z; a[s][9] = u2.w;
  }
  float M = m[0];
#pragma unroll
  for (int s = 1; s < NSPLIT; ++s) M = fmaxf(M, m[s]);
  float L = 0.f;
  float o[10];
#pragma unroll
  for (int d = 0; d < 10; ++d) o[d] = 0.f;
#pragma unroll
  for (int s = 0; s < NSPLIT; ++s) {
    float al = __expf(m[s] - M);
    L += l[s] * al;
#pragma unroll
    for (int d = 0; d < 10; ++d) o[d] += a[s][d] * al;
  }
  float inv = 1.f / L;
  // attn_pre flat (b,hd,n,d): base = (qid>>10)*10240 + (qid&1023)*10
  float* ob = attn_pre + (size_t)(qid >> 10) * 10240 + (size_t)(qid & 1023) * 10;
#pragma unroll
  for (int d = 0; d < 10; ++d) ob[d] = o[d] * inv;
}

// ---------------- pool attn ----------------
__global__ __launch_bounds__(256) void pool_attn_kernel(
    const float* __restrict__ attn_pre, float* __restrict__ pooledA) {
  int bc = blockIdx.x;
  const float* p = attn_pre + bc * 1024;
  int t = threadIdx.x;
  float s = 0.f;
  for (int j = t; j < 1024; j += 256) s += p[j];
  __shared__ float red[256];
  red[t] = s;
  __syncthreads();
  for (int off = 128; off > 0; off >>= 1) {
    if (t < off) red[t] += red[t + off];
    __syncthreads();
  }
  if (t == 0) pooledA[bc] = red[0] * (1.f / 1024.f);
}

// ---------------- final: pooled convo matvec + attno + fc ----------------
__global__ __launch_bounds__(128) void final_kernel(
    const float* __restrict__ Sstat, const float* __restrict__ pooledA,
    const float* __restrict__ convo_w, const float* __restrict__ convo_b,
    const float* __restrict__ attno_w, const float* __restrict__ attno_b,
    const float* __restrict__ fc_w, const float* __restrict__ fc_b,
    float* __restrict__ out) {
  int b = blockIdx.x;
  int t = threadIdx.x;
  __shared__ float Sl[576];
  __shared__ float pooled[128];
  __shared__ float pa[40];
  for (int j = t; j < 576; j += 128) Sl[j] = Sstat[b * 576 + j];
  if (t < 40) pa[t] = pooledA[b * 40 + t];
  __syncthreads();
  if (t < 88) {
    float acc = 0.f;
    for (int j = 0; j < 576; ++j) acc += convo_w[t * 576 + j] * Sl[j];
    pooled[t] = convo_b[t] + acc * (1.f / 1024.f);
  } else if (t < 128) {
    int co = t - 88;
    float acc = attno_b[co];
    for (int ci = 0; ci < 40; ++ci) acc += attno_w[co * 40 + ci] * pa[ci];
    pooled[88 + co] = acc;
  }
  __syncthreads();
  if (t < 100) {
    float acc = fc_b[t];
    for (int c = 0; c < 128; ++c) acc += fc_w[t * 128 + c] * pooled[c];
    out[b * 100 + t] = acc;
  }
}

extern "C" void kernel_launch(void* const* d_in, const int* in_sizes, int n_in,
                              void* d_out, int out_size, void* d_ws, size_t ws_size,
                              hipStream_t stream) {
  const float* x        = (const float*)d_in[0];
  const float* conv1_w  = (const float*)d_in[1];
  const float* conv1_b  = (const float*)d_in[2];
  const float* bn1_g    = (const float*)d_in[3];
  const float* bn1_b    = (const float*)d_in[4];
  const float* convo_w  = (const float*)d_in[5];
  const float* convo_b  = (const float*)d_in[6];
  const float* qkv_w    = (const float*)d_in[7];
  const float* qkv_b    = (const float*)d_in[8];
  const float* attno_w  = (const float*)d_in[9];
  const float* attno_b  = (const float*)d_in[10];
  const float* key_rel_h = (const float*)d_in[11];
  const float* key_rel_w = (const float*)d_in[12];
  const float* fc_w     = (const float*)d_in[13];
  const float* fc_b     = (const float*)d_in[14];

  float* ws       = (float*)d_ws;
  float* h        = ws + WS_H;
  float* qkvb     = ws + WS_QKV;
  float* attn_pre = ws + WS_ATTN;
  float* scale    = ws + WS_SCALE;
  float* shift    = ws + WS_SHIFT;
  float* Sstat    = ws + WS_SSTAT;
  float* pooledA  = ws + WS_POOLA;
  float* part     = ws + WS_PART;

  conv1_kernel<<<1024, 256, 0, stream>>>(x, conv1_w, conv1_b, h);
  bn_stats_kernel<<<64, 256, 0, stream>>>(h, bn1_g, bn1_b, scale, shift);
  bn_apply_kernel<<<1024, 256, 0, stream>>>(h, scale, shift);
  sstat_kernel<<<1024, 256, 0, stream>>>(h, Sstat);
  qkv_kernel<<<7680, 256, 0, stream>>>(h, qkv_w, qkv_b, qkvb);
  attn_split_kernel<<<16 * 4 * 4 * NSPLIT, 256, 0, stream>>>(qkvb, key_rel_w, key_rel_h, part);
  attn_combine_kernel<<<256, 256, 0, stream>>>(part, attn_pre);
  pool_attn_kernel<<<640, 256, 0, stream>>>(attn_pre, pooledA);
  final_kernel<<<16, 128, 0, stream>>>(Sstat, pooledA, convo_w, convo_b,
                                       attno_w, attno_b, fc_w, fc_b, (float*)d_out);
}